// Round 10
// baseline (1599.757 us; speedup 1.0000x reference)
//
#include <hip/hip_runtime.h>
#include <hip/hip_cooperative_groups.h>
#include <cstddef>
#include <cstdint>

namespace cg = cooperative_groups;

#define Bn 2
#define Sn 1500
#define SPn 1536
#define Cn 1024
#define Hn 16
#define FFn 4096

typedef __attribute__((ext_vector_type(8))) short bf16x8;
typedef __attribute__((ext_vector_type(4))) float f32x4;
typedef unsigned short u16;
typedef unsigned int u32;

__device__ __forceinline__ u16 f2bu(float f) {
  unsigned u = __float_as_uint(f);
  return (u16)((u + 0x7fffu + ((u >> 16) & 1u)) >> 16);
}
__device__ __forceinline__ float bu2f(u16 v) {
  return __uint_as_float(((u32)v) << 16);
}

__device__ __forceinline__ void gl_lds16(const u16* g, u16* l) {
  __builtin_amdgcn_global_load_lds(
      (__attribute__((address_space(1))) void*)(uintptr_t)g,
      (__attribute__((address_space(3))) void*)(u32)(uintptr_t)l,
      16, 0, 0);
}

// =================== phase bodies (shared by classic + mega paths) ===================

// pre: [0,192) gate | [192,3264) transpose+cast | [3264,15555) weight cast/bias
__device__ __forceinline__ void phase_pre(
    int bid, const float* __restrict__ x,
    const float* __restrict__ Wq, const float* __restrict__ Wk,
    const float* __restrict__ Wv, const float* __restrict__ Wo,
    const float* __restrict__ W1, const float* __restrict__ W2,
    const float* __restrict__ bq, const float* __restrict__ bk,
    const float* __restrict__ bv,
    const float* __restrict__ Wg, const float* __restrict__ bg,
    const float* __restrict__ gc,
    float* __restrict__ xT, u16* __restrict__ xTb,
    u16* __restrict__ wqkvb, u16* __restrict__ wob,
    u16* __restrict__ w1b, u16* __restrict__ w2b, float* __restrict__ bqkv,
    float* __restrict__ gate, char* smem)
{
  if (bid < 192) {
    const int b = bid / 96, h = (bid / 6) & 15;
    const int s = (bid % 6) * 256 + threadIdx.x;
    const bool vld = s < Sn;
    const float* xp = x + ((size_t)b * Cn + h * 64) * Sn + (vld ? s : 0);
    float dot[8];
#pragma unroll
    for (int o = 0; o < 8; o++) dot[o] = 0.f;
#pragma unroll 4
    for (int d = 0; d < 64; d++) {
      float v = xp[(size_t)d * Sn];
#pragma unroll
      for (int o = 0; o < 8; o++) dot[o] += Wg[o * 64 + d] * v;
    }
    float sa = dot[0] + dot[1] + dot[2] + dot[3] + bg[0] + bg[1] + bg[2] + bg[3];
    float sb = dot[4] + dot[5] + dot[6] + dot[7] + bg[4] + bg[5] + bg[6] + bg[7];
    float ga = 1.f / (1.f + __expf(-sa));
    float gb = 1.f / (1.f + __expf(-sb));
    float gv = ga * (gb * gc[h] - 1.f) + 2.f;
    gate[((size_t)b * Hn + h) * SPn + s] = vld ? gv : 0.f;
    return;
  }
  if (bid < 3264) {
    float (*t)[33] = (float(*)[33])smem;
    const int tb = bid - 192;
    const int c0 = (tb & 31) * 32, s0 = ((tb >> 5) % 48) * 32, b = tb / 1536;
    const int tx = threadIdx.x & 31, ty = threadIdx.x >> 5;
#pragma unroll
    for (int i = 0; i < 32; i += 8) {
      int c = c0 + ty + i, s = s0 + tx;
      t[ty + i][tx] = (s < Sn) ? x[((size_t)b * Cn + c) * Sn + s] : 0.f;
    }
    __syncthreads();
#pragma unroll
    for (int i = 0; i < 32; i += 8) {
      int s = s0 + ty + i, c = c0 + tx;
      float v = t[tx][ty + i];
      size_t o = ((size_t)b * SPn + s) * Cn + c;
      xT[o] = v;
      xTb[o] = f2bu(v);
    }
    return;
  }
  {
    int i = (bid - 3264) * 256 + threadIdx.x;
    const float* src;
    u16* dst;
    int j;
    if (i < 786432) {
      src = (i < 262144) ? Wq : ((i < 524288) ? Wk : Wv);
      j = i & 262143;
      dst = wqkvb + (size_t)i * 4;
    } else if (i < 1048576) {
      src = Wo; j = i - 786432; dst = wob + (size_t)j * 4;
    } else if (i < 2097152) {
      src = W1; j = i - 1048576; dst = w1b + (size_t)j * 4;
    } else if (i < 3145728) {
      src = W2; j = i - 2097152; dst = w2b + (size_t)j * 4;
    } else {
      int k = i - 3145728;
      const float* bsrc = (k < 256) ? bq : ((k < 512) ? bk : bv);
      float4 v = *(const float4*)(bsrc + (k & 255) * 4);
      *(float4*)(bqkv + k * 4) = v;
      return;
    }
    float4 v = *(const float4*)(src + (size_t)j * 4);
    ushort4 o;
    o.x = f2bu(v.x); o.y = f2bu(v.y); o.z = f2bu(v.z); o.w = f2bu(v.w);
    *(ushort4*)dst = o;
  }
}

__device__ __forceinline__ void phase_tout(
    int vb, const float* __restrict__ oT, float* __restrict__ o, char* smem)
{
  float (*t)[33] = (float(*)[33])smem;
  const int c0 = (vb & 31) * 32, s0 = ((vb >> 5) % 48) * 32, b = vb / 1536;
  const int tx = threadIdx.x & 31, ty = threadIdx.x >> 5;
#pragma unroll
  for (int i = 0; i < 32; i += 8) {
    int s = s0 + ty + i, c = c0 + tx;
    t[ty + i][tx] = oT[((size_t)b * SPn + s) * Cn + c];
  }
  __syncthreads();
#pragma unroll
  for (int i = 0; i < 32; i += 8) {
    int c = c0 + ty + i, s = s0 + tx;
    if (s < Sn) o[((size_t)b * Cn + c) * Sn + s] = t[tx][ty + i];
  }
}

template <int EPI, int SPLIT, int TM>
__device__ __forceinline__ void phase_gemm(
    int mx, int sy, int zz,
    const u16* __restrict__ A, const u16* __restrict__ X,
    const float* __restrict__ bias, void* __restrict__ out, void* __restrict__ out2,
    u16* __restrict__ vT, int M, int Kst, int Ktot, char* smem)
{
  constexpr int NI = TM / 32;
  const int b = zz / SPLIT, half = zz % SPLIT;
  const int Kc = Ktot / SPLIT;
  const int m0 = mx * TM;
  const int s0 = sy * 128;
  const int tid = threadIdx.x;
  const int lane = tid & 63;
  const int wid = tid >> 6;
  const int wm = (wid >> 1) * (TM / 2);
  const int wn = (wid & 1) * 64;
  const int l15 = lane & 15;
  const int g4 = lane >> 4;

  u16 (*lA)[64] = (u16(*)[64])smem;
  u16 (*lX)[64] = (u16(*)[64])(smem + TM * 128);

  f32x4 acc[NI][4];
  f32x4 zr; zr[0] = 0.f; zr[1] = 0.f; zr[2] = 0.f; zr[3] = 0.f;
#pragma unroll
  for (int i = 0; i < NI; i++)
#pragma unroll
    for (int j = 0; j < 4; j++) acc[i][j] = zr;

  const int rlo = lane >> 3;
  const int cg = (lane & 7) ^ rlo;
  const int kbeg = half * Kc;
  const u16* gA = A + (size_t)(m0 + wid * (TM / 4) + rlo) * Kst + cg * 8 + kbeg;
  const u16* gX = X + ((size_t)b * SPn + s0 + wid * 32 + rlo) * Kst + cg * 8 + kbeg;
  u16* lAp = &lA[0][0] + wid * (TM / 4) * 64;
  u16* lXp = &lX[0][0] + wid * 2048;
  const size_t rstep8 = (size_t)8 * Kst;

  for (int kt = 0; kt < Kc; kt += 64) {
    __syncthreads();
#pragma unroll
    for (int j = 0; j < TM / 32; j++)
      gl_lds16(gA + j * rstep8 + kt, lAp + j * 512);
#pragma unroll
    for (int j = 0; j < 4; j++)
      gl_lds16(gX + j * rstep8 + kt, lXp + j * 512);
    __syncthreads();
#pragma unroll
    for (int ks = 0; ks < 2; ks++) {
      bf16x8 af[NI], bfr[4];
#pragma unroll
      for (int i = 0; i < NI; i++) {
        int ra = wm + i * 16 + l15;
        af[i] = *(const bf16x8*)&lA[ra][((ks * 4 + g4) ^ (ra & 7)) * 8];
      }
#pragma unroll
      for (int j = 0; j < 4; j++) {
        int rb = wn + j * 16 + l15;
        bfr[j] = *(const bf16x8*)&lX[rb][((ks * 4 + g4) ^ (rb & 7)) * 8];
      }
#pragma unroll
      for (int i = 0; i < NI; i++)
#pragma unroll
        for (int j = 0; j < 4; j++)
          acc[i][j] = __builtin_amdgcn_mfma_f32_16x16x32_bf16(af[i], bfr[j], acc[i][j], 0, 0, 0);
    }
  }

  const float hsc = (half == 0) ? 1.f : 0.f;
  void* outp = (half == 0) ? out : out2;
#pragma unroll
  for (int i = 0; i < NI; i++) {
    int o = m0 + wm + i * 16 + g4 * 4;
    float4 bs = *(const float4*)(bias + o);
#pragma unroll
    for (int j = 0; j < 4; j++) {
      int s = s0 + wn + j * 16 + l15;
      size_t oidx = ((size_t)b * SPn + s) * M + o;
      f32x4 v = acc[i][j];
      float x0 = v[0] + bs.x * hsc, x1 = v[1] + bs.y * hsc;
      float x2 = v[2] + bs.z * hsc, x3 = v[3] + bs.w * hsc;
      if (EPI == 0) {
        float4 st; st.x = x0; st.y = x1; st.z = x2; st.w = x3;
        *(float4*)((float*)outp + oidx) = st;
      } else if (EPI == 1) {
        x0 = 0.5f * x0 * (1.f + erff(x0 * 0.70710678118654752f));
        x1 = 0.5f * x1 * (1.f + erff(x1 * 0.70710678118654752f));
        x2 = 0.5f * x2 * (1.f + erff(x2 * 0.70710678118654752f));
        x3 = 0.5f * x3 * (1.f + erff(x3 * 0.70710678118654752f));
        ushort4 st;
        st.x = f2bu(x0); st.y = f2bu(x1); st.z = f2bu(x2); st.w = f2bu(x3);
        *(ushort4*)((u16*)outp + oidx) = st;
      } else {
        ushort4 st;
        st.x = f2bu(x0); st.y = f2bu(x1); st.z = f2bu(x2); st.w = f2bu(x3);
        if (vT != nullptr && o >= 2048) {
          int oo = o - 2048;
          int h = oo >> 6, d = oo & 63;
          u16* vp = vT + ((size_t)(b * Hn + h) * 64 + d) * SPn + s;
          vp[0] = st.x;
          vp[SPn] = st.y;
          vp[2 * SPn] = st.z;
          vp[3 * SPn] = st.w;
        } else {
          *(ushort4*)((u16*)outp + oidx) = st;
        }
      }
    }
  }
}

// flash smem layout: kls 0..9216 | vls ..18432 | pls ..27648 | pbs ..45312 | kpm ..51456
__device__ __forceinline__ void phase_flash(
    int qt, int bh,
    const u16* __restrict__ qkv, const u16* __restrict__ vT,
    const float* __restrict__ pb, const float* __restrict__ am,
    const float* __restrict__ gate, u16* __restrict__ ctx, char* smem)
{
  const int b = bh >> 4, h = bh & 15;
  const int q0 = qt * 64;
  const int tid = threadIdx.x;
  const int lane = tid & 63, wid = tid >> 6;
  const int l15 = lane & 15, g4 = lane >> 4;
  const int q = q0 + wid * 16 + l15;

  u16 (*kls)[72] = (u16(*)[72])smem;
  u16 (*vls)[72] = (u16(*)[72])(smem + 9216);
  u16 (*pls)[16][72] = (u16(*)[16][72])(smem + 18432);
  float (*pbs)[16][69] = (float(*)[16][69])(smem + 27648);
  float* kpm = (float*)(smem + 45312);

  const int r0 = tid >> 3, c80 = (tid & 7) * 8;
  const int r1 = (256 + tid) >> 3, c81 = c80;
  const u16* kg0 = qkv + ((size_t)b * SPn + r0) * 3072 + 1024 + h * 64 + c80;
  const u16* kg1 = qkv + ((size_t)b * SPn + r1) * 3072 + 1024 + h * 64 + c81;
  const u16* vg0 = vT + ((size_t)bh * 64 + r0) * SPn + c80;
  const u16* vg1 = vT + ((size_t)bh * 64 + r1) * SPn + c81;

  const int prow = lane >> 4;
  const int pcol = l15 * 4;
  int pbq[4];
#pragma unroll
  for (int j = 0; j < 4; j++) {
    int qq = q0 + wid * 16 + j * 4 + prow;
    pbq[j] = (qq < Sn) ? qq : (Sn - 1);
  }
  const float* pbbase = pb + (size_t)bh * Sn * Sn;

  bf16x8 qf[2];
  {
    const u16* qp = qkv + ((size_t)b * SPn + q) * 3072 + h * 64 + g4 * 8;
    qf[0] = *(const bf16x8*)qp;
    qf[1] = *(const bf16x8*)(qp + 32);
  }
  const float gr = gate[(size_t)bh * SPn + q];

  {
    int4 k0v = *(const int4*)kg0;
    int4 k1v = *(const int4*)kg1;
    int4 v0v = *(const int4*)vg0;
    int4 v1v = *(const int4*)vg1;
#pragma unroll
    for (int j = 0; j < 6; j++) {
      int idx = tid + j * 256;
      kpm[idx] = (idx < Sn) ? (1.f - am[b * Sn + idx]) * -10000.f : -1e30f;
    }
    *(int4*)&kls[r0][c80] = k0v;
    *(int4*)&kls[r1][c81] = k1v;
    *(int4*)&vls[r0][c80] = v0v;
    *(int4*)&vls[r1][c81] = v1v;
  }
  __syncthreads();

  float m = -3.0e38f, l = 0.f;
  f32x4 accO[4];
  f32x4 zr; zr[0] = 0.f; zr[1] = 0.f; zr[2] = 0.f; zr[3] = 0.f;
#pragma unroll
  for (int i = 0; i < 4; i++) accO[i] = zr;

  for (int kt = 0; kt < 24; kt++) {
    const int k0 = kt * 64;
    int4 krn0, krn1, vrn0, vrn1;
    if (kt < 23) {
      const int k0n = k0 + 64;
      krn0 = *(const int4*)(kg0 + (size_t)k0n * 3072);
      krn1 = *(const int4*)(kg1 + (size_t)k0n * 3072);
      vrn0 = *(const int4*)(vg0 + k0n);
      vrn1 = *(const int4*)(vg1 + k0n);
    }
    if (kt < 23) {
#pragma unroll
      for (int j = 0; j < 4; j++) {
        float4 pv = *(const float4*)(pbbase + (size_t)pbq[j] * Sn + k0 + pcol);
        *(float4*)&pbs[wid][j * 4 + prow][pcol] = pv;
      }
    } else {
#pragma unroll
      for (int j = 0; j < 4; j++) {
        float4 pv;
        int kk = k0 + pcol;
        const float* pr = pbbase + (size_t)pbq[j] * Sn;
        pv.x = (kk + 0 < Sn) ? pr[kk + 0] : 0.f;
        pv.y = (kk + 1 < Sn) ? pr[kk + 1] : 0.f;
        pv.z = (kk + 2 < Sn) ? pr[kk + 2] : 0.f;
        pv.w = (kk + 3 < Sn) ? pr[kk + 3] : 0.f;
        *(float4*)&pbs[wid][j * 4 + prow][pcol] = pv;
      }
    }

    f32x4 sAcc[4];
    __builtin_amdgcn_s_setprio(1);
#pragma unroll
    for (int km = 0; km < 4; km++) {
      sAcc[km] = zr;
#pragma unroll
      for (int dc = 0; dc < 2; dc++) {
        bf16x8 af = *(const bf16x8*)&kls[km * 16 + l15][dc * 32 + g4 * 8];
        sAcc[km] = __builtin_amdgcn_mfma_f32_16x16x32_bf16(af, qf[dc], sAcc[km], 0, 0, 0);
      }
    }
    __builtin_amdgcn_s_setprio(0);

    float sc[16];
#pragma unroll
    for (int km = 0; km < 4; km++) {
      int kk = k0 + km * 16 + g4 * 4;
      float4 kp = *(const float4*)&kpm[kk];
      float4 pbv = *(const float4*)&pbs[wid][l15][km * 16 + g4 * 4];
      sc[km * 4 + 0] = sAcc[km][0] * 0.125f + gr * pbv.x + kp.x;
      sc[km * 4 + 1] = sAcc[km][1] * 0.125f + gr * pbv.y + kp.y;
      sc[km * 4 + 2] = sAcc[km][2] * 0.125f + gr * pbv.z + kp.z;
      sc[km * 4 + 3] = sAcc[km][3] * 0.125f + gr * pbv.w + kp.w;
    }

    float mloc = sc[0];
#pragma unroll
    for (int i = 1; i < 16; i++) mloc = fmaxf(mloc, sc[i]);
    mloc = fmaxf(mloc, __shfl_xor(mloc, 16));
    mloc = fmaxf(mloc, __shfl_xor(mloc, 32));

    if (mloc > m + 8.f) {
      float corr = __expf(m - mloc);
      m = mloc;
      l *= corr;
#pragma unroll
      for (int i = 0; i < 4; i++) {
        accO[i][0] *= corr; accO[i][1] *= corr;
        accO[i][2] *= corr; accO[i][3] *= corr;
      }
    }

    float ls = 0.f;
#pragma unroll
    for (int i = 0; i < 16; i++) {
      float p = __expf(sc[i] - m);
      sc[i] = p;
      ls += p;
    }
    ls += __shfl_xor(ls, 16);
    ls += __shfl_xor(ls, 32);
    l += ls;

#pragma unroll
    for (int km = 0; km < 4; km++) {
      u32 lo = (u32)f2bu(sc[km * 4 + 0]) | ((u32)f2bu(sc[km * 4 + 1]) << 16);
      u32 hi = (u32)f2bu(sc[km * 4 + 2]) | ((u32)f2bu(sc[km * 4 + 3]) << 16);
      u32* dst = (u32*)&pls[wid][l15][km * 16 + g4 * 4];
      dst[0] = lo; dst[1] = hi;
    }

    bf16x8 pf[2];
    pf[0] = *(const bf16x8*)&pls[wid][l15][g4 * 8];
    pf[1] = *(const bf16x8*)&pls[wid][l15][32 + g4 * 8];
    __builtin_amdgcn_s_setprio(1);
#pragma unroll
    for (int dm = 0; dm < 4; dm++) {
#pragma unroll
      for (int kc = 0; kc < 2; kc++) {
        bf16x8 af = *(const bf16x8*)&vls[dm * 16 + l15][kc * 32 + g4 * 8];
        accO[dm] = __builtin_amdgcn_mfma_f32_16x16x32_bf16(af, pf[kc], accO[dm], 0, 0, 0);
      }
    }
    __builtin_amdgcn_s_setprio(0);

    __syncthreads();
    if (kt < 23) {
      *(int4*)&kls[r0][c80] = krn0;
      *(int4*)&kls[r1][c81] = krn1;
      *(int4*)&vls[r0][c80] = vrn0;
      *(int4*)&vls[r1][c81] = vrn1;
      __syncthreads();
    }
  }

  float inv = 1.f / l;
  const bool qv = q < Sn;
#pragma unroll
  for (int dm = 0; dm < 4; dm++) {
    ushort4 st;
    st.x = f2bu(qv ? accO[dm][0] * inv : 0.f);
    st.y = f2bu(qv ? accO[dm][1] * inv : 0.f);
    st.z = f2bu(qv ? accO[dm][2] * inv : 0.f);
    st.w = f2bu(qv ? accO[dm][3] * inv : 0.f);
    *(ushort4*)(ctx + ((size_t)b * SPn + q) * Cn + h * 64 + dm * 16 + g4 * 4) = st;
  }
}

__device__ __forceinline__ void phase_ln3(
    int s, int b,
    const float* __restrict__ r1, const u16* __restrict__ r2,
    const u16* __restrict__ r3,
    const float* __restrict__ g, const float* __restrict__ be,
    float* __restrict__ outF, u16* __restrict__ outB, char* smem)
{
  float* red = (float*)smem;
  const size_t base = ((size_t)b * SPn + s) * Cn;
  const int tid = threadIdx.x;
  const int c = tid * 4;
  float4 a = *(const float4*)(r1 + base + c);
  ushort4 v2 = *(const ushort4*)(r2 + base + c);
  ushort4 v3 = *(const ushort4*)(r3 + base + c);
  float t0 = a.x + bu2f(v2.x) + bu2f(v3.x);
  float t1 = a.y + bu2f(v2.y) + bu2f(v3.y);
  float t2 = a.z + bu2f(v2.z) + bu2f(v3.z);
  float t3 = a.w + bu2f(v2.w) + bu2f(v3.w);
  float sum = t0 + t1 + t2 + t3;
#pragma unroll
  for (int mk = 1; mk < 64; mk <<= 1) sum += __shfl_xor(sum, mk);
  if ((tid & 63) == 0) red[tid >> 6] = sum;
  __syncthreads();
  float mu = (red[0] + red[1] + red[2] + red[3]) * (1.f / Cn);
  float d0 = t0 - mu, d1 = t1 - mu, d2 = t2 - mu, d3 = t3 - mu;
  float vs = d0 * d0 + d1 * d1 + d2 * d2 + d3 * d3;
#pragma unroll
  for (int mk = 1; mk < 64; mk <<= 1) vs += __shfl_xor(vs, mk);
  if ((tid & 63) == 0) red[4 + (tid >> 6)] = vs;
  __syncthreads();
  float var = (red[4] + red[5] + red[6] + red[7]) * (1.f / Cn);
  float rstd = rsqrtf(var + 1e-5f);
  float4 gv = *(const float4*)(g + c);
  float4 bv = *(const float4*)(be + c);
  float o0 = d0 * rstd * gv.x + bv.x;
  float o1 = d1 * rstd * gv.y + bv.y;
  float o2 = d2 * rstd * gv.z + bv.z;
  float o3 = d3 * rstd * gv.w + bv.w;
  float4 st; st.x = o0; st.y = o1; st.z = o2; st.w = o3;
  *(float4*)(outF + base + c) = st;
  if (outB) {
    ushort4 sb;
    sb.x = f2bu(o0); sb.y = f2bu(o1); sb.z = f2bu(o2); sb.w = f2bu(o3);
    *(ushort4*)(outB + base + c) = sb;
  }
}

// =================== classic (fallback) kernels ===================

__global__ __launch_bounds__(256) void k_pre(
    const float* x, const float* Wq, const float* Wk, const float* Wv,
    const float* Wo, const float* W1, const float* W2,
    const float* bq, const float* bk, const float* bv,
    const float* Wg, const float* bg, const float* gc,
    float* xT, u16* xTb, u16* wqkvb, u16* wob, u16* w1b, u16* w2b,
    float* bqkv, float* gate)
{
  __shared__ __align__(16) char smem[4224];
  phase_pre(blockIdx.x, x, Wq, Wk, Wv, Wo, W1, W2, bq, bk, bv, Wg, bg, gc,
            xT, xTb, wqkvb, wob, w1b, w2b, bqkv, gate, smem);
}

__global__ __launch_bounds__(256) void k_transpose_out(
    const float* oT, float* o)
{
  __shared__ __align__(16) char smem[4224];
  int vb = blockIdx.x + 32 * blockIdx.y + 1536 * blockIdx.z;
  phase_tout(vb, oT, o, smem);
}

template <int EPI, int SPLIT, int TM>
__global__ __launch_bounds__(256) void k_gemm(
    const u16* A, const u16* X, const float* bias, void* out, void* out2,
    u16* vT, int M, int Kst, int Ktot)
{
  __shared__ __align__(16) char smem[TM * 128 + 16384];
  phase_gemm<EPI, SPLIT, TM>(blockIdx.x, blockIdx.y, blockIdx.z,
                             A, X, bias, out, out2, vT, M, Kst, Ktot, smem);
}

__global__ __launch_bounds__(256) void k_flash_mfma(
    const u16* qkv, const u16* vT, const float* pb, const float* am,
    const float* gate, u16* ctx)
{
  __shared__ __align__(16) char smem[51456];
  phase_flash(blockIdx.x, blockIdx.y, qkv, vT, pb, am, gate, ctx, smem);
}

__global__ __launch_bounds__(256) void k_ln3(
    const float* r1, const u16* r2, const u16* r3,
    const float* g, const float* be, float* outF, u16* outB)
{
  __shared__ __align__(16) char smem[32];
  phase_ln3(blockIdx.x, blockIdx.y, r1, r2, r3, g, be, outF, outB, smem);
}

// =================== cooperative mega-kernel ===================

struct MegaArgs {
  const float *x, *am, *pb;
  const float *Wq, *Wk, *Wv, *Wo, *W1, *W2, *Wg;
  const float *bq, *bk, *bv, *bo, *bg, *gc;
  const float *ln1g, *ln1b, *b1, *b2, *ln2g, *ln2b;
  float *xT; u16 *xTb, *wqkvb, *wob, *w1b, *w2b;
  float *bqkv, *gate;
  u16 *qkvB, *vT, *attnTa, *attnTb, *ctxT;
  float *hT; u16 *hTb, *fT, *f2Ta, *f2Tb;
  float *outT, *out;
};

__global__ __launch_bounds__(256, 3) void k_mega(MegaArgs P)
{
  __shared__ __align__(16) char smem[51456];
  const int bid = blockIdx.x;
  cg::grid_group grid = cg::this_grid();

  // P0: preamble
  for (int vb = bid; vb < 15555; vb += 768) {
    phase_pre(vb, P.x, P.Wq, P.Wk, P.Wv, P.Wo, P.W1, P.W2, P.bq, P.bk, P.bv,
              P.Wg, P.bg, P.gc, P.xT, P.xTb, P.wqkvb, P.wob, P.w1b, P.w2b,
              P.bqkv, P.gate, smem);
    __syncthreads();
  }
  __threadfence();
  grid.sync();

  // P1: QKV (TM=96, 768 blocks)
  {
    int mx = bid & 31, sy = (bid >> 5) % 12, b = bid / 384;
    phase_gemm<2, 1, 96>(mx, sy, b, P.wqkvb, P.xTb, P.bqkv, P.qkvB, P.qkvB,
                         P.vT, 3072, 1024, 1024, smem);
  }
  __threadfence();
  grid.sync();

  // P2: flash (768 blocks)
  {
    int qt = bid % 24, bh = bid / 24;
    phase_flash(qt, bh, P.qkvB, P.vT, P.pb, P.am, P.gate, P.ctxT, smem);
  }
  __threadfence();
  grid.sync();

  // P3: Wo (TM=64, split2)
  {
    int mx = bid & 15, sy = (bid >> 4) % 12, zz = bid / 192;
    phase_gemm<2, 2, 64>(mx, sy, zz, P.wob, P.ctxT, P.bo, P.attnTa, P.attnTb,
                         (u16*)nullptr, 1024, 1024, 1024, smem);
  }
  __threadfence();
  grid.sync();

  // P4: LN1
  for (int vb = bid; vb < 3072; vb += 768) {
    phase_ln3(vb % 1536, vb / 1536, P.xT, P.attnTa, P.attnTb, P.ln1g, P.ln1b,
              P.hT, P.hTb, smem);
    __syncthreads();
  }
  __threadfence();
  grid.sync();

  // P5: FFN1 (TM=128)
  {
    int mx = bid & 31, sy = (bid >> 5) % 12, b = bid / 384;
    phase_gemm<1, 1, 128>(mx, sy, b, P.w1b, P.hTb, P.b1, P.fT, P.fT,
                          (u16*)nullptr, 4096, 1024, 1024, smem);
  }
  __threadfence();
  grid.sync();

  // P6: FFN2 (TM=64, split2)
  {
    int mx = bid & 15, sy = (bid >> 4) % 12, zz = bid / 192;
    phase_gemm<2, 2, 64>(mx, sy, zz, P.w2b, P.fT, P.b2, P.f2Ta, P.f2Tb,
                         (u16*)nullptr, 1024, 4096, 4096, smem);
  }
  __threadfence();
  grid.sync();

  // P7: LN2
  for (int vb = bid; vb < 3072; vb += 768) {
    phase_ln3(vb % 1536, vb / 1536, P.hT, P.f2Ta, P.f2Tb, P.ln2g, P.ln2b,
              P.outT, (u16*)nullptr, smem);
    __syncthreads();
  }
  __threadfence();
  grid.sync();

  // P8: transpose out
  for (int vb = bid; vb < 3072; vb += 768) {
    phase_tout(vb, P.outT, P.out, smem);
    __syncthreads();
  }
}

extern "C" void kernel_launch(void* const* d_in, const int* in_sizes, int n_in,
                              void* d_out, int out_size, void* d_ws, size_t ws_size,
                              hipStream_t stream)
{
  const float* x    = (const float*)d_in[0];
  const float* am   = (const float*)d_in[1];
  const float* pb   = (const float*)d_in[2];
  const float* Wq   = (const float*)d_in[3];
  const float* bq   = (const float*)d_in[4];
  const float* Wk   = (const float*)d_in[5];
  const float* bk   = (const float*)d_in[6];
  const float* Wv   = (const float*)d_in[7];
  const float* bv   = (const float*)d_in[8];
  const float* Wo   = (const float*)d_in[9];
  const float* bo   = (const float*)d_in[10];
  const float* Wg   = (const float*)d_in[11];
  const float* bg   = (const float*)d_in[12];
  const float* gc   = (const float*)d_in[13];
  const float* ln1g = (const float*)d_in[14];
  const float* ln1b = (const float*)d_in[15];
  const float* W1   = (const float*)d_in[16];
  const float* b1   = (const float*)d_in[17];
  const float* W2   = (const float*)d_in[18];
  const float* b2   = (const float*)d_in[19];
  const float* ln2g = (const float*)d_in[20];
  const float* ln2b = (const float*)d_in[21];

  char* ws = (char*)d_ws;
  float* xT     = (float*)(ws + 0);
  u16*   xTb    = (u16*)(ws + 12582912);
  u16*   wqkvb  = (u16*)(ws + 18874368);
  u16*   wob    = (u16*)(ws + 25165824);
  u16*   w1b    = (u16*)(ws + 27262976);
  u16*   w2b    = (u16*)(ws + 35651584);
  float* bqkv   = (float*)(ws + 44040192);
  float* gate   = (float*)(ws + 44052480);
  u16*   qkvB   = (u16*)(ws + 44249088);
  u16*   vT     = (u16*)(ws + 63123456);
  u16*   attnTa = (u16*)(ws + 69414912);
  u16*   attnTb = (u16*)(ws + 81997824);
  u16*   ctxT   = xTb;
  float* hT     = (float*)(ws + 44249088);
  u16*   hTb    = wqkvb;
  u16*   fT     = (u16*)(ws + 56832000);
  u16*   f2Ta   = (u16*)(ws + 0);
  u16*   f2Tb   = (u16*)(ws + 81997824);
  float* outT   = (float*)(ws + 12582912);

  MegaArgs P;
  P.x = x; P.am = am; P.pb = pb;
  P.Wq = Wq; P.Wk = Wk; P.Wv = Wv; P.Wo = Wo; P.W1 = W1; P.W2 = W2; P.Wg = Wg;
  P.bq = bq; P.bk = bk; P.bv = bv; P.bo = bo; P.bg = bg; P.gc = gc;
  P.ln1g = ln1g; P.ln1b = ln1b; P.b1 = b1; P.b2 = b2; P.ln2g = ln2g; P.ln2b = ln2b;
  P.xT = xT; P.xTb = xTb; P.wqkvb = wqkvb; P.wob = wob; P.w1b = w1b; P.w2b = w2b;
  P.bqkv = bqkv; P.gate = gate;
  P.qkvB = qkvB; P.vT = vT; P.attnTa = attnTa; P.attnTb = attnTb; P.ctxT = ctxT;
  P.hT = hT; P.hTb = hTb; P.fT = fT; P.f2Ta = f2Ta; P.f2Tb = f2Tb;
  P.outT = outT; P.out = (float*)d_out;

  void* kargs[] = { (void*)&P };
  hipError_t err = hipLaunchCooperativeKernel((const void*)k_mega, dim3(768),
                                              dim3(256), kargs, 0, stream);
  if (err == hipSuccess) return;
  (void)hipGetLastError();  // clear error state, fall back to classic path

  dim3 blk(256);
  k_pre<<<dim3(15555), blk, 0, stream>>>(x, Wq, Wk, Wv, Wo, W1, W2, bq, bk, bv,
                                         Wg, bg, gc, xT, xTb, wqkvb, wob, w1b,
                                         w2b, bqkv, gate);
  k_gemm<2, 1, 96><<<dim3(32, 12, Bn), blk, 0, stream>>>(
      wqkvb, xTb, bqkv, qkvB, qkvB, vT, 3072, 1024, 1024);
  k_flash_mfma<<<dim3(SPn / 64, Bn * Hn), blk, 0, stream>>>(qkvB, vT, pb, am, gate, ctxT);
  k_gemm<2, 2, 64><<<dim3(16, 12, Bn * 2), blk, 0, stream>>>(
      wob, ctxT, bo, attnTa, attnTb, (u16*)nullptr, 1024, 1024, 1024);
  k_ln3<<<dim3(SPn, Bn), blk, 0, stream>>>(xT, attnTa, attnTb, ln1g, ln1b, hT, hTb);
  k_gemm<1, 1, 128><<<dim3(32, 12, Bn), blk, 0, stream>>>(
      w1b, hTb, b1, fT, fT, (u16*)nullptr, 4096, 1024, 1024);
  k_gemm<2, 2, 64><<<dim3(16, 12, Bn * 2), blk, 0, stream>>>(
      w2b, fT, b2, f2Ta, f2Tb, (u16*)nullptr, 1024, 4096, 4096);
  k_ln3<<<dim3(SPn, Bn), blk, 0, stream>>>(hT, f2Ta, f2Tb, ln2g, ln2b, outT, (u16*)nullptr);
  k_transpose_out<<<dim3(Cn / 32, SPn / 32, Bn), blk, 0, stream>>>(outT, (float*)d_out);
}

// Round 11
// 259.312 us; speedup vs baseline: 6.1692x; 6.1692x over previous
//
#include <hip/hip_runtime.h>
#include <cstddef>
#include <cstdint>

#define Bn 2
#define Sn 1500
#define SPn 1536
#define Cn 1024
#define Hn 16
#define FFn 4096

typedef __attribute__((ext_vector_type(8))) short bf16x8;
typedef __attribute__((ext_vector_type(4))) float f32x4;
typedef unsigned short u16;
typedef unsigned int u32;

__device__ __forceinline__ u16 f2bu(float f) {
  unsigned u = __float_as_uint(f);
  return (u16)((u + 0x7fffu + ((u >> 16) & 1u)) >> 16);
}
__device__ __forceinline__ float bu2f(u16 v) {
  return __uint_as_float(((u32)v) << 16);
}

__device__ __forceinline__ void gl_lds16(const u16* g, u16* l) {
  __builtin_amdgcn_global_load_lds(
      (__attribute__((address_space(1))) void*)(uintptr_t)g,
      (__attribute__((address_space(3))) void*)(u32)(uintptr_t)l,
      16, 0, 0);
}

// ---------------- fused preamble: gate + transpose_in(bf16 only) + weight prep ----------------
// segments (blockIdx.x): [0,192) gate | [192,3264) transpose+cast | [3264,15555) weight cast/bias
__global__ __launch_bounds__(256) void k_pre(
    const float* __restrict__ x,
    const float* __restrict__ Wq, const float* __restrict__ Wk,
    const float* __restrict__ Wv, const float* __restrict__ Wo,
    const float* __restrict__ W1, const float* __restrict__ W2,
    const float* __restrict__ bq, const float* __restrict__ bk,
    const float* __restrict__ bv,
    const float* __restrict__ Wg, const float* __restrict__ bg,
    const float* __restrict__ gc,
    u16* __restrict__ xTb,
    u16* __restrict__ wqkvb, u16* __restrict__ wob,
    u16* __restrict__ w1b, u16* __restrict__ w2b, float* __restrict__ bqkv,
    float* __restrict__ gate)
{
  const int bid = blockIdx.x;
  if (bid < 192) {
    // ---- gate (first: long-latency loop overlaps the bulk) ----
    const int b = bid / 96, h = (bid / 6) & 15;
    const int s = (bid % 6) * 256 + threadIdx.x;
    const bool vld = s < Sn;
    const float* xp = x + ((size_t)b * Cn + h * 64) * Sn + (vld ? s : 0);
    float dot[8];
#pragma unroll
    for (int o = 0; o < 8; o++) dot[o] = 0.f;
#pragma unroll 4
    for (int d = 0; d < 64; d++) {
      float v = xp[(size_t)d * Sn];
#pragma unroll
      for (int o = 0; o < 8; o++) dot[o] += Wg[o * 64 + d] * v;
    }
    float sa = dot[0] + dot[1] + dot[2] + dot[3] + bg[0] + bg[1] + bg[2] + bg[3];
    float sb = dot[4] + dot[5] + dot[6] + dot[7] + bg[4] + bg[5] + bg[6] + bg[7];
    float ga = 1.f / (1.f + __expf(-sa));
    float gb = 1.f / (1.f + __expf(-sb));
    float gv = ga * (gb * gc[h] - 1.f) + 2.f;
    gate[((size_t)b * Hn + h) * SPn + s] = vld ? gv : 0.f;
    return;
  }
  if (bid < 3264) {
    // ---- transpose + cast (bf16 only; f32 copy dropped) ----
    __shared__ float t[32][33];
    const int tb = bid - 192;
    const int c0 = (tb & 31) * 32, s0 = ((tb >> 5) % 48) * 32, b = tb / 1536;
    const int tx = threadIdx.x & 31, ty = threadIdx.x >> 5;
#pragma unroll
    for (int i = 0; i < 32; i += 8) {
      int c = c0 + ty + i, s = s0 + tx;
      t[ty + i][tx] = (s < Sn) ? x[((size_t)b * Cn + c) * Sn + s] : 0.f;
    }
    __syncthreads();
#pragma unroll
    for (int i = 0; i < 32; i += 8) {
      int s = s0 + ty + i, c = c0 + tx;
      xTb[((size_t)b * SPn + s) * Cn + c] = f2bu(t[tx][ty + i]);
    }
    return;
  }
  {
    // ---- weight cast / bias pack ----
    int i = (bid - 3264) * 256 + threadIdx.x;
    const float* src;
    u16* dst;
    int j;
    if (i < 786432) {
      src = (i < 262144) ? Wq : ((i < 524288) ? Wk : Wv);
      j = i & 262143;
      dst = wqkvb + (size_t)i * 4;
    } else if (i < 1048576) {
      src = Wo; j = i - 786432; dst = wob + (size_t)j * 4;
    } else if (i < 2097152) {
      src = W1; j = i - 1048576; dst = w1b + (size_t)j * 4;
    } else if (i < 3145728) {
      src = W2; j = i - 2097152; dst = w2b + (size_t)j * 4;
    } else {
      int k = i - 3145728;
      const float* bsrc = (k < 256) ? bq : ((k < 512) ? bk : bv);
      float4 v = *(const float4*)(bsrc + (k & 255) * 4);
      *(float4*)(bqkv + k * 4) = v;
      return;
    }
    float4 v = *(const float4*)(src + (size_t)j * 4);
    ushort4 o;
    o.x = f2bu(v.x); o.y = f2bu(v.y); o.z = f2bu(v.z); o.w = f2bu(v.w);
    *(ushort4*)dst = o;
  }
}

// ---------------- transpose output: outT (B,SP,C) -> out (B,C,S) ----------------
__global__ __launch_bounds__(256) void k_transpose_out(
    const float* __restrict__ oT, float* __restrict__ o)
{
  __shared__ float t[32][33];
  const int b = blockIdx.z, c0 = blockIdx.x * 32, s0 = blockIdx.y * 32;
  const int tx = threadIdx.x & 31, ty = threadIdx.x >> 5;
#pragma unroll
  for (int i = 0; i < 32; i += 8) {
    int s = s0 + ty + i, c = c0 + tx;
    t[ty + i][tx] = oT[((size_t)b * SPn + s) * Cn + c];
  }
  __syncthreads();
#pragma unroll
  for (int i = 0; i < 32; i += 8) {
    int c = c0 + ty + i, s = s0 + tx;
    if (s < Sn) o[((size_t)b * Cn + c) * Sn + s] = t[tx][ty + i];
  }
}

// ---------------- bf16 MFMA GEMM, BK=64, global_load_lds staging, tile TM x 128 ----------------
// EPI: 0 = f32 out, 1 = gelu -> bf16, 2 = bf16 out (+ optional V-part scatter to vT,
//       in which case the V region is NOT written to the main output)
template <int EPI, int SPLIT, int TM>
__global__ __launch_bounds__(256) void k_gemm(
    const u16* __restrict__ A, const u16* __restrict__ X,
    const float* __restrict__ bias, void* __restrict__ out, void* __restrict__ out2,
    u16* __restrict__ vT, int M, int Kst, int Ktot)
{
  constexpr int NI = TM / 32;
  const int zz = blockIdx.z;
  const int b = zz / SPLIT, half = zz % SPLIT;
  const int Kc = Ktot / SPLIT;
  const int m0 = blockIdx.x * TM;
  const int s0 = blockIdx.y * 128;
  const int tid = threadIdx.x;
  const int lane = tid & 63;
  const int wid = tid >> 6;
  const int wm = (wid >> 1) * (TM / 2);
  const int wn = (wid & 1) * 64;
  const int l15 = lane & 15;
  const int g4 = lane >> 4;

  __shared__ __align__(16) u16 lA[TM][64];
  __shared__ __align__(16) u16 lX[128][64];

  f32x4 acc[NI][4];
  f32x4 zr; zr[0] = 0.f; zr[1] = 0.f; zr[2] = 0.f; zr[3] = 0.f;
#pragma unroll
  for (int i = 0; i < NI; i++)
#pragma unroll
    for (int j = 0; j < 4; j++) acc[i][j] = zr;

  const int rlo = lane >> 3;
  const int cg = (lane & 7) ^ rlo;
  const int kbeg = half * Kc;
  const u16* gA = A + (size_t)(m0 + wid * (TM / 4) + rlo) * Kst + cg * 8 + kbeg;
  const u16* gX = X + ((size_t)b * SPn + s0 + wid * 32 + rlo) * Kst + cg * 8 + kbeg;
  u16* lAp = &lA[0][0] + wid * (TM / 4) * 64;
  u16* lXp = &lX[0][0] + wid * 2048;
  const size_t rstep8 = (size_t)8 * Kst;

  for (int kt = 0; kt < Kc; kt += 64) {
    __syncthreads();
#pragma unroll
    for (int j = 0; j < TM / 32; j++)
      gl_lds16(gA + j * rstep8 + kt, lAp + j * 512);
#pragma unroll
    for (int j = 0; j < 4; j++)
      gl_lds16(gX + j * rstep8 + kt, lXp + j * 512);
    __syncthreads();
#pragma unroll
    for (int ks = 0; ks < 2; ks++) {
      bf16x8 af[NI], bfr[4];
#pragma unroll
      for (int i = 0; i < NI; i++) {
        int ra = wm + i * 16 + l15;
        af[i] = *(const bf16x8*)&lA[ra][((ks * 4 + g4) ^ (ra & 7)) * 8];
      }
#pragma unroll
      for (int j = 0; j < 4; j++) {
        int rb = wn + j * 16 + l15;
        bfr[j] = *(const bf16x8*)&lX[rb][((ks * 4 + g4) ^ (rb & 7)) * 8];
      }
#pragma unroll
      for (int i = 0; i < NI; i++)
#pragma unroll
        for (int j = 0; j < 4; j++)
          acc[i][j] = __builtin_amdgcn_mfma_f32_16x16x32_bf16(af[i], bfr[j], acc[i][j], 0, 0, 0);
    }
  }

  const float hsc = (half == 0) ? 1.f : 0.f;
  void* outp = (half == 0) ? out : out2;
#pragma unroll
  for (int i = 0; i < NI; i++) {
    int o = m0 + wm + i * 16 + g4 * 4;
    float4 bs = *(const float4*)(bias + o);
#pragma unroll
    for (int j = 0; j < 4; j++) {
      int s = s0 + wn + j * 16 + l15;
      size_t oidx = ((size_t)b * SPn + s) * M + o;
      f32x4 v = acc[i][j];
      float x0 = v[0] + bs.x * hsc, x1 = v[1] + bs.y * hsc;
      float x2 = v[2] + bs.z * hsc, x3 = v[3] + bs.w * hsc;
      if (EPI == 0) {
        float4 st; st.x = x0; st.y = x1; st.z = x2; st.w = x3;
        *(float4*)((float*)outp + oidx) = st;
      } else if (EPI == 1) {
        x0 = 0.5f * x0 * (1.f + erff(x0 * 0.70710678118654752f));
        x1 = 0.5f * x1 * (1.f + erff(x1 * 0.70710678118654752f));
        x2 = 0.5f * x2 * (1.f + erff(x2 * 0.70710678118654752f));
        x3 = 0.5f * x3 * (1.f + erff(x3 * 0.70710678118654752f));
        ushort4 st;
        st.x = f2bu(x0); st.y = f2bu(x1); st.z = f2bu(x2); st.w = f2bu(x3);
        *(ushort4*)((u16*)outp + oidx) = st;
      } else {
        ushort4 st;
        st.x = f2bu(x0); st.y = f2bu(x1); st.z = f2bu(x2); st.w = f2bu(x3);
        if (vT != nullptr && o >= 2048) {
          int oo = o - 2048;
          int h = oo >> 6, d = oo & 63;
          u16* vp = vT + ((size_t)(b * Hn + h) * 64 + d) * SPn + s;
          vp[0] = st.x;
          vp[SPn] = st.y;
          vp[2 * SPn] = st.z;
          vp[3 * SPn] = st.w;
        } else {
          *(ushort4*)((u16*)outp + oidx) = st;
        }
      }
    }
  }
}

// ---------------- MFMA flash attention, T14 K/V pipeline + LDS-coalesced pb ----------------
__global__ __launch_bounds__(256) void k_flash_mfma(
    const u16* __restrict__ qkv,    // [B][SP][3072] bf16 (Q|K|-)
    const u16* __restrict__ vT,     // [BH][64][SP] bf16
    const float* __restrict__ pb,   // [BH][S][S] f32
    const float* __restrict__ am,   // [B][S]
    const float* __restrict__ gate, // [BH][SP]
    u16* __restrict__ ctx)          // [B][SP][C] bf16
{
  const int bh = blockIdx.y, b = bh >> 4, h = bh & 15;
  const int q0 = blockIdx.x * 64;
  const int tid = threadIdx.x;
  const int lane = tid & 63, wid = tid >> 6;
  const int l15 = lane & 15, g4 = lane >> 4;
  const int q = q0 + wid * 16 + l15;

  __shared__ __align__(16) u16 kls[64][72];
  __shared__ __align__(16) u16 vls[64][72];
  __shared__ __align__(16) u16 pls[4][16][72];
  __shared__ float pbs[4][16][69];
  __shared__ float kpm[SPn];

  const int r0 = tid >> 3, c80 = (tid & 7) * 8;
  const int r1 = (256 + tid) >> 3, c81 = c80;
  const u16* kg0 = qkv + ((size_t)b * SPn + r0) * 3072 + 1024 + h * 64 + c80;
  const u16* kg1 = qkv + ((size_t)b * SPn + r1) * 3072 + 1024 + h * 64 + c81;
  const u16* vg0 = vT + ((size_t)bh * 64 + r0) * SPn + c80;
  const u16* vg1 = vT + ((size_t)bh * 64 + r1) * SPn + c81;

  const int prow = lane >> 4;
  const int pcol = l15 * 4;
  int pbq[4];
#pragma unroll
  for (int j = 0; j < 4; j++) {
    int qq = q0 + wid * 16 + j * 4 + prow;
    pbq[j] = (qq < Sn) ? qq : (Sn - 1);
  }
  const float* pbbase = pb + (size_t)bh * Sn * Sn;

  bf16x8 qf[2];
  {
    const u16* qp = qkv + ((size_t)b * SPn + q) * 3072 + h * 64 + g4 * 8;
    qf[0] = *(const bf16x8*)qp;
    qf[1] = *(const bf16x8*)(qp + 32);
  }
  const float gr = gate[(size_t)bh * SPn + q];

  {
    int4 k0v = *(const int4*)kg0;
    int4 k1v = *(const int4*)kg1;
    int4 v0v = *(const int4*)vg0;
    int4 v1v = *(const int4*)vg1;
#pragma unroll
    for (int j = 0; j < 6; j++) {
      int idx = tid + j * 256;
      kpm[idx] = (idx < Sn) ? (1.f - am[b * Sn + idx]) * -10000.f : -1e30f;
    }
    *(int4*)&kls[r0][c80] = k0v;
    *(int4*)&kls[r1][c81] = k1v;
    *(int4*)&vls[r0][c80] = v0v;
    *(int4*)&vls[r1][c81] = v1v;
  }
  __syncthreads();

  float m = -3.0e38f, l = 0.f;
  f32x4 accO[4];
  f32x4 zr; zr[0] = 0.f; zr[1] = 0.f; zr[2] = 0.f; zr[3] = 0.f;
#pragma unroll
  for (int i = 0; i < 4; i++) accO[i] = zr;

  for (int kt = 0; kt < 24; kt++) {
    const int k0 = kt * 64;
    int4 krn0, krn1, vrn0, vrn1;
    if (kt < 23) {
      const int k0n = k0 + 64;
      krn0 = *(const int4*)(kg0 + (size_t)k0n * 3072);
      krn1 = *(const int4*)(kg1 + (size_t)k0n * 3072);
      vrn0 = *(const int4*)(vg0 + k0n);
      vrn1 = *(const int4*)(vg1 + k0n);
    }
    if (kt < 23) {
#pragma unroll
      for (int j = 0; j < 4; j++) {
        float4 pv = *(const float4*)(pbbase + (size_t)pbq[j] * Sn + k0 + pcol);
        *(float4*)&pbs[wid][j * 4 + prow][pcol] = pv;
      }
    } else {
#pragma unroll
      for (int j = 0; j < 4; j++) {
        float4 pv;
        int kk = k0 + pcol;
        const float* pr = pbbase + (size_t)pbq[j] * Sn;
        pv.x = (kk + 0 < Sn) ? pr[kk + 0] : 0.f;
        pv.y = (kk + 1 < Sn) ? pr[kk + 1] : 0.f;
        pv.z = (kk + 2 < Sn) ? pr[kk + 2] : 0.f;
        pv.w = (kk + 3 < Sn) ? pr[kk + 3] : 0.f;
        *(float4*)&pbs[wid][j * 4 + prow][pcol] = pv;
      }
    }

    f32x4 sAcc[4];
    __builtin_amdgcn_s_setprio(1);
#pragma unroll
    for (int km = 0; km < 4; km++) {
      sAcc[km] = zr;
#pragma unroll
      for (int dc = 0; dc < 2; dc++) {
        bf16x8 af = *(const bf16x8*)&kls[km * 16 + l15][dc * 32 + g4 * 8];
        sAcc[km] = __builtin_amdgcn_mfma_f32_16x16x32_bf16(af, qf[dc], sAcc[km], 0, 0, 0);
      }
    }
    __builtin_amdgcn_s_setprio(0);

    float sc[16];
#pragma unroll
    for (int km = 0; km < 4; km++) {
      int kk = k0 + km * 16 + g4 * 4;
      float4 kp = *(const float4*)&kpm[kk];
      float4 pbv = *(const float4*)&pbs[wid][l15][km * 16 + g4 * 4];
      sc[km * 4 + 0] = sAcc[km][0] * 0.125f + gr * pbv.x + kp.x;
      sc[km * 4 + 1] = sAcc[km][1] * 0.125f + gr * pbv.y + kp.y;
      sc[km * 4 + 2] = sAcc[km][2] * 0.125f + gr * pbv.z + kp.z;
      sc[km * 4 + 3] = sAcc[km][3] * 0.125f + gr * pbv.w + kp.w;
    }

    float mloc = sc[0];
#pragma unroll
    for (int i = 1; i < 16; i++) mloc = fmaxf(mloc, sc[i]);
    mloc = fmaxf(mloc, __shfl_xor(mloc, 16));
    mloc = fmaxf(mloc, __shfl_xor(mloc, 32));

    if (mloc > m + 8.f) {
      float corr = __expf(m - mloc);
      m = mloc;
      l *= corr;
#pragma unroll
      for (int i = 0; i < 4; i++) {
        accO[i][0] *= corr; accO[i][1] *= corr;
        accO[i][2] *= corr; accO[i][3] *= corr;
      }
    }

    float ls = 0.f;
#pragma unroll
    for (int i = 0; i < 16; i++) {
      float p = __expf(sc[i] - m);
      sc[i] = p;
      ls += p;
    }
    ls += __shfl_xor(ls, 16);
    ls += __shfl_xor(ls, 32);
    l += ls;

#pragma unroll
    for (int km = 0; km < 4; km++) {
      u32 lo = (u32)f2bu(sc[km * 4 + 0]) | ((u32)f2bu(sc[km * 4 + 1]) << 16);
      u32 hi = (u32)f2bu(sc[km * 4 + 2]) | ((u32)f2bu(sc[km * 4 + 3]) << 16);
      u32* dst = (u32*)&pls[wid][l15][km * 16 + g4 * 4];
      dst[0] = lo; dst[1] = hi;
    }

    bf16x8 pf[2];
    pf[0] = *(const bf16x8*)&pls[wid][l15][g4 * 8];
    pf[1] = *(const bf16x8*)&pls[wid][l15][32 + g4 * 8];
    __builtin_amdgcn_s_setprio(1);
#pragma unroll
    for (int dm = 0; dm < 4; dm++) {
#pragma unroll
      for (int kc = 0; kc < 2; kc++) {
        bf16x8 af = *(const bf16x8*)&vls[dm * 16 + l15][kc * 32 + g4 * 8];
        accO[dm] = __builtin_amdgcn_mfma_f32_16x16x32_bf16(af, pf[kc], accO[dm], 0, 0, 0);
      }
    }
    __builtin_amdgcn_s_setprio(0);

    __syncthreads();
    if (kt < 23) {
      *(int4*)&kls[r0][c80] = krn0;
      *(int4*)&kls[r1][c81] = krn1;
      *(int4*)&vls[r0][c80] = vrn0;
      *(int4*)&vls[r1][c81] = vrn1;
      __syncthreads();
    }
  }

  float inv = 1.f / l;
  const bool qv = q < Sn;
#pragma unroll
  for (int dm = 0; dm < 4; dm++) {
    ushort4 st;
    st.x = f2bu(qv ? accO[dm][0] * inv : 0.f);
    st.y = f2bu(qv ? accO[dm][1] * inv : 0.f);
    st.z = f2bu(qv ? accO[dm][2] * inv : 0.f);
    st.w = f2bu(qv ? accO[dm][3] * inv : 0.f);
    *(ushort4*)(ctx + ((size_t)b * SPn + q) * Cn + h * 64 + dm * 16 + g4 * 4) = st;
  }
}

// ---------------- fused 3-way residual + LayerNorm over C ----------------
// R1BF: r1 is bf16 (LN1: r1 = xTb) or f32 (LN2: r1 = hT)
template <bool R1BF>
__global__ __launch_bounds__(256) void k_ln3(
    const void* __restrict__ r1v, const u16* __restrict__ r2,
    const u16* __restrict__ r3,
    const float* __restrict__ g, const float* __restrict__ be,
    float* __restrict__ outF, u16* __restrict__ outB)
{
  const int s = blockIdx.x, b = blockIdx.y;
  const size_t base = ((size_t)b * SPn + s) * Cn;
  __shared__ float red[8];
  const int tid = threadIdx.x;
  const int c = tid * 4;
  float a0, a1, a2, a3;
  if (R1BF) {
    ushort4 v1 = *(const ushort4*)((const u16*)r1v + base + c);
    a0 = bu2f(v1.x); a1 = bu2f(v1.y); a2 = bu2f(v1.z); a3 = bu2f(v1.w);
  } else {
    float4 a = *(const float4*)((const float*)r1v + base + c);
    a0 = a.x; a1 = a.y; a2 = a.z; a3 = a.w;
  }
  ushort4 v2 = *(const ushort4*)(r2 + base + c);
  ushort4 v3 = *(const ushort4*)(r3 + base + c);
  float t0 = a0 + bu2f(v2.x) + bu2f(v3.x);
  float t1 = a1 + bu2f(v2.y) + bu2f(v3.y);
  float t2 = a2 + bu2f(v2.z) + bu2f(v3.z);
  float t3 = a3 + bu2f(v2.w) + bu2f(v3.w);
  float sum = t0 + t1 + t2 + t3;
#pragma unroll
  for (int mk = 1; mk < 64; mk <<= 1) sum += __shfl_xor(sum, mk);
  if ((tid & 63) == 0) red[tid >> 6] = sum;
  __syncthreads();
  float mu = (red[0] + red[1] + red[2] + red[3]) * (1.f / Cn);
  float d0 = t0 - mu, d1 = t1 - mu, d2 = t2 - mu, d3 = t3 - mu;
  float vs = d0 * d0 + d1 * d1 + d2 * d2 + d3 * d3;
#pragma unroll
  for (int mk = 1; mk < 64; mk <<= 1) vs += __shfl_xor(vs, mk);
  if ((tid & 63) == 0) red[4 + (tid >> 6)] = vs;
  __syncthreads();
  float var = (red[4] + red[5] + red[6] + red[7]) * (1.f / Cn);
  float rstd = rsqrtf(var + 1e-5f);
  float4 gv = *(const float4*)(g + c);
  float4 bv = *(const float4*)(be + c);
  float o0 = d0 * rstd * gv.x + bv.x;
  float o1 = d1 * rstd * gv.y + bv.y;
  float o2 = d2 * rstd * gv.z + bv.z;
  float o3 = d3 * rstd * gv.w + bv.w;
  float4 st; st.x = o0; st.y = o1; st.z = o2; st.w = o3;
  *(float4*)(outF + base + c) = st;
  if (outB) {
    ushort4 sb;
    sb.x = f2bu(o0); sb.y = f2bu(o1); sb.z = f2bu(o2); sb.w = f2bu(o3);
    *(ushort4*)(outB + base + c) = sb;
  }
}

extern "C" void kernel_launch(void* const* d_in, const int* in_sizes, int n_in,
                              void* d_out, int out_size, void* d_ws, size_t ws_size,
                              hipStream_t stream)
{
  const float* x    = (const float*)d_in[0];
  const float* am   = (const float*)d_in[1];
  const float* pb   = (const float*)d_in[2];
  const float* Wq   = (const float*)d_in[3];
  const float* bq   = (const float*)d_in[4];
  const float* Wk   = (const float*)d_in[5];
  const float* bk   = (const float*)d_in[6];
  const float* Wv   = (const float*)d_in[7];
  const float* bv   = (const float*)d_in[8];
  const float* Wo   = (const float*)d_in[9];
  const float* bo   = (const float*)d_in[10];
  const float* Wg   = (const float*)d_in[11];
  const float* bg   = (const float*)d_in[12];
  const float* gc   = (const float*)d_in[13];
  const float* ln1g = (const float*)d_in[14];
  const float* ln1b = (const float*)d_in[15];
  const float* W1   = (const float*)d_in[16];
  const float* b1   = (const float*)d_in[17];
  const float* W2   = (const float*)d_in[18];
  const float* b2   = (const float*)d_in[19];
  const float* ln2g = (const float*)d_in[20];
  const float* ln2b = (const float*)d_in[21];

  // workspace arena (lifetime-aliased)
  char* ws = (char*)d_ws;
  u16*   ctxT   = (u16*)(ws + 0);              // [flash .. Wo] (6.3 MB)
  u16*   xTb    = (u16*)(ws + 12582912);       // [pre .. LN1]  -> outT [LN2..tout]
  u16*   wqkvb  = (u16*)(ws + 18874368);       // [pre .. QKV]  -> hTb [LN1..FFN1]
  u16*   wob    = (u16*)(ws + 25165824);
  u16*   w1b    = (u16*)(ws + 27262976);
  u16*   w2b    = (u16*)(ws + 35651584);
  float* bqkv   = (float*)(ws + 44040192);
  float* gate   = (float*)(ws + 44052480);
  u16*   qkvB   = (u16*)(ws + 44249088);       // [QKV .. flash]; then hT f32 [LN1..LN2]
  u16*   vT     = (u16*)(ws + 63123456);       // [QKV .. flash]
  u16*   attnTa = (u16*)(ws + 69414912);       // [Wo .. LN1] bf16
  u16*   attnTb = (u16*)(ws + 81997824);       // [Wo .. LN1] bf16
  float* hT     = (float*)(ws + 44249088);
  u16*   hTb    = wqkvb;
  u16*   fT     = (u16*)(ws + 56832000);       // [FFN1 .. FFN2]
  u16*   f2Ta   = (u16*)(ws + 0);              // [FFN2 .. LN2] bf16 (ctxT dead)
  u16*   f2Tb   = (u16*)(ws + 81997824);       // [FFN2 .. LN2] bf16
  float* outT   = (float*)(ws + 12582912);     // [LN2 .. tout] (xTb dead)

  dim3 blk(256);
  k_pre<<<dim3(15555), blk, 0, stream>>>(x, Wq, Wk, Wv, Wo, W1, W2, bq, bk, bv,
                                         Wg, bg, gc, xTb, wqkvb, wob, w1b,
                                         w2b, bqkv, gate);

  // QKV projection -> bf16 (+fused V^T): M=3072, K=1024, TM=96 -> 768 blocks
  k_gemm<2, 1, 96><<<dim3(32, 12, Bn), blk, 0, stream>>>(
      wqkvb, xTb, bqkv, qkvB, qkvB, vT, 3072, 1024, 1024);
  // MFMA flash attention (768 blocks)
  k_flash_mfma<<<dim3(SPn / 64, Bn * Hn), blk, 0, stream>>>(qkvB, vT, pb, am, gate, ctxT);
  // Wo: M=1024, K=1024, TM=64, split-K=2 -> 768 blocks, bf16 partials
  k_gemm<2, 2, 64><<<dim3(16, 12, Bn * 2), blk, 0, stream>>>(
      wob, ctxT, bo, attnTa, attnTb, (u16*)nullptr, 1024, 1024, 1024);
  // LN1 = LN(x(bf16) + attnA + attnB) -> hT (f32) + hTb (bf16)
  k_ln3<true><<<dim3(SPn, Bn), blk, 0, stream>>>(xTb, attnTa, attnTb, ln1g, ln1b, hT, hTb);
  // FFN1 + gelu -> fT (bf16): M=4096, K=1024, TM=128 -> 768 blocks
  k_gemm<1, 1, 128><<<dim3(32, 12, Bn), blk, 0, stream>>>(
      w1b, hTb, b1, fT, fT, (u16*)nullptr, 4096, 1024, 1024);
  // FFN2: M=1024, K=4096, TM=64, split-K=2 -> 768 blocks, bf16 partials
  k_gemm<2, 2, 64><<<dim3(16, 12, Bn * 2), blk, 0, stream>>>(
      w2b, fT, b2, f2Ta, f2Tb, (u16*)nullptr, 1024, 4096, 4096);
  // LN2 = LN(h(f32) + f2a + f2b) -> outT
  k_ln3<false><<<dim3(SPn, Bn), blk, 0, stream>>>(hT, f2Ta, f2Tb, ln2g, ln2b, outT, (u16*)nullptr);
  // back to (B,C,1,S)
  k_transpose_out<<<dim3(Cn / 32, SPn / 32, Bn), blk, 0, stream>>>(outT, (float*)d_out);
}